// Round 3
// baseline (228.813 us; speedup 1.0000x reference)
//
#include <hip/hip_runtime.h>

// SSIM loss: Xt, Yt are [B=16, C=1, T=20, H=256, W=256] fp32.
// Frame f = b*20 + t contiguous 65536 floats. dr[t] = max over Yt[:,:,t].
// S per 7x7 valid window (250x250/frame); out = 1 - mean(S).

#define HH 256
#define WW 256
#define OUTW 250
#define NT 20
#define NB 16
#define NFRAMES (NT * NB)        // 320
#define STRIPS 25
#define RPS 10                   // output rows per strip (25*10 = 250), even
#define NWAVES (NFRAMES * STRIPS) // 8000
#define WPB 4                    // waves per block
#define NBLK2 (NWAVES / WPB)     // 2000

__device__ __forceinline__ float wave_sum(float v) {
#pragma unroll
    for (int off = 32; off > 0; off >>= 1) v += __shfl_down(v, off, 64);
    return v;
}

// ---------------- Pass 1: per-t max over Yt (quarter-frame blocks) ----------
// R9: no atomic, no memset node. Each block writes its max to a distinct slot
// dr_part[t*64 + bq]; ssim waves reduce the 64 slots (1 load + 6 shfl_xor).
__global__ __launch_bounds__(256) void dr_max_kernel(const float* __restrict__ Y,
                                                     float* __restrict__ dr_part) {
    int t = blockIdx.x;          // 0..19
    int bq = blockIdx.y;         // 0..63 : b = bq>>2, quarter = bq&3
    const float4* p = (const float4*)(Y + (size_t)((bq >> 2) * NT + t) * (HH * WW))
                      + (bq & 3) * 4096;
    float m = 0.f;               // inputs uniform [0,1) => non-negative
#pragma unroll 4
    for (int k = 0; k < 16; ++k) {
        float4 v = p[k * 256 + threadIdx.x];
        m = fmaxf(m, fmaxf(fmaxf(v.x, v.y), fmaxf(v.z, v.w)));
    }
#pragma unroll
    for (int off = 32; off > 0; off >>= 1) m = fmaxf(m, __shfl_down(m, off, 64));
    __shared__ float smax[4];
    int lane = threadIdx.x & 63, w = threadIdx.x >> 6;
    if (lane == 0) smax[w] = m;
    __syncthreads();
    if (threadIdx.x == 0)
        dr_part[t * 64 + bq] = fmaxf(fmaxf(smax[0], smax[1]), fmaxf(smax[2], smax[3]));
}

// ---------------- Pass 2: SSIM, 4 independent waves/block ------------------
// Each wave owns one (frame, strip); 64 lanes x 4 cols = 256 cols.
// Vertical 7-row running sums in registers; horizontal 7-tap via shuffles
// (zero LDS allocation -> occupancy not LDS-limited).
// R9: TWO output rows per iteration. R0 (8 waves/CU x 2-row ILP) and R8
// (13 waves x 1-row) tied at ~58us => bottleneck is independent-chain count,
// not occupancy alone. 2 rows/iter at 13 waves/CU doubles chains (~26/CU)
// and doubles in-flight load bytes (8 float4/iter) for Little's law.
// Keep __launch_bounds__(256,4) (VGPR cap 128): R7 proved a 7-wave cap
// spills to scratch (572 MB scratch writes, 335us).

// S scaled by 49^2 top & bottom (cancels): c1=2401*C1, c2=2401*C2.
__device__ __forceinline__ float ssim_px(float hx, float hy, float hxx, float hyy,
                                         float hxy, float c1, float c2) {
    const float cov = 49.0f / 48.0f;
    float hx2 = hx * hx, hy2 = hy * hy, hxy1 = hx * hy;
    float A1 = __builtin_fmaf(2.f, hxy1, c1);
    float B1 = hx2 + hy2 + c1;
    float t1 = __builtin_fmaf(49.f, hxx, -hx2);
    float t2 = __builtin_fmaf(49.f, hyy, -hy2);
    float t3 = __builtin_fmaf(49.f, hxy, -hxy1);
    float A2 = __builtin_fmaf(2.f * cov, t3, c2);
    float B2 = __builtin_fmaf(cov, t1 + t2, c2);
    return (A1 * A2) * __builtin_amdgcn_rcpf(B1 * B2);
}

// 7-tap horizontal sums for 4 consecutive output cols via cross-lane shuffles:
//   P = s.x+s.y+s.z+s.w;  P1 = P(lane+1), w1 = s.w(lane+1),
//   x2 = s.x(lane+2), y2 = s.y(lane+2)
//   o0 = P + P1 - w1; o1 = P + P1 - s.x; o2 = s.z+s.w+P1+x2; o3 = s.w+P1+x2+y2
// Lane 62: o0,o1 use lane-63 values (valid), o2,o3 masked. Lane 63: all masked.
__device__ __forceinline__ float4 taps7_shfl(float4 s) {
    float P  = (s.x + s.y) + (s.z + s.w);
    float P1 = __shfl_down(P,   1, 64);
    float w1 = __shfl_down(s.w, 1, 64);
    float x2 = __shfl_down(s.x, 2, 64);
    float y2 = __shfl_down(s.y, 2, 64);
    float base = P + P1;
    float o0 = base - w1;
    float o1 = base - s.x;
    float o2 = s.z + s.w + P1 + x2;
    float o3 = o2 - s.z + y2;          // s.w + P1 + x2 + y2
    return make_float4(o0, o1, o2, o3);
}

__device__ __forceinline__ void slide5(float4& sx, float4& sy, float4& sxx,
                                       float4& syy, float4& sxy,
                                       float4 xo, float4 yo, float4 xn, float4 yn) {
    sx.x += xn.x - xo.x; sx.y += xn.y - xo.y; sx.z += xn.z - xo.z; sx.w += xn.w - xo.w;
    sy.x += yn.x - yo.x; sy.y += yn.y - yo.y; sy.z += yn.z - yo.z; sy.w += yn.w - yo.w;
    sxx.x += xn.x * xn.x - xo.x * xo.x; sxx.y += xn.y * xn.y - xo.y * xo.y;
    sxx.z += xn.z * xn.z - xo.z * xo.z; sxx.w += xn.w * xn.w - xo.w * xo.w;
    syy.x += yn.x * yn.x - yo.x * yo.x; syy.y += yn.y * yn.y - yo.y * yo.y;
    syy.z += yn.z * yn.z - yo.z * yo.z; syy.w += yn.w * yn.w - yo.w * yo.w;
    sxy.x += xn.x * yn.x - xo.x * yo.x; sxy.y += xn.y * yn.y - xo.y * yo.y;
    sxy.z += xn.z * yn.z - xo.z * yo.z; sxy.w += xn.w * yn.w - xo.w * yo.w;
}

__global__ __launch_bounds__(256, 4) void ssim_kernel(const float* __restrict__ X,
                                                      const float* __restrict__ Y,
                                                      const float* __restrict__ dr_part,
                                                      float* __restrict__ partials) {
    int w = threadIdx.x >> 6;
    int l = threadIdx.x & 63;
    int wid = blockIdx.x * WPB + w;
    int frame = wid / STRIPS;   // 0..319
    int strip = wid % STRIPS;
    int t = frame % NT;
    const float4* x4 = (const float4*)(X + (size_t)frame * (HH * WW));
    const float4* y4 = (const float4*)(Y + (size_t)frame * (HH * WW));
    int c0 = 4 * l;

    // dr[t] = max of the 64 per-block partial maxes (one per lane, butterfly)
    float dr = dr_part[t * 64 + l];
#pragma unroll
    for (int off = 32; off > 0; off >>= 1) dr = fmaxf(dr, __shfl_xor(dr, off, 64));
    float c1 = 2401.f * (0.01f * dr) * (0.01f * dr);
    float c2 = 2401.f * (0.03f * dr) * (0.03f * dr);

    int r0 = strip * RPS;

    // vertical running column-sums (4 cols/lane) over rows r0..r0+6
    float4 sx = make_float4(0, 0, 0, 0), sy = sx, sxx = sx, syy = sx, sxy = sx;
#pragma unroll
    for (int dy = 0; dy < 7; ++dy) {
        float4 xv = x4[(r0 + dy) * 64 + l];
        float4 yv = y4[(r0 + dy) * 64 + l];
        sx.x += xv.x; sx.y += xv.y; sx.z += xv.z; sx.w += xv.w;
        sy.x += yv.x; sy.y += yv.y; sy.z += yv.z; sy.w += yv.w;
        sxx.x += xv.x * xv.x; sxx.y += xv.y * xv.y; sxx.z += xv.z * xv.z; sxx.w += xv.w * xv.w;
        syy.x += yv.x * yv.x; syy.y += yv.y * yv.y; syy.z += yv.z * yv.z; syy.w += yv.w * yv.w;
        sxy.x += xv.x * yv.x; sxy.y += xv.y * yv.y; sxy.z += xv.z * yv.z; sxy.w += xv.w * yv.w;
    }

    float acc = 0.f;
    for (int it = 0; it < RPS / 2; ++it) {
        int r = r0 + 2 * it;       // rows r and r+1 this iteration
        bool lastit = (it == RPS / 2 - 1);

        // issue all slide loads up front (latency hidden under shfl + math)
        float4 xa = x4[r * 64 + l],       ya = y4[r * 64 + l];        // old, slide1
        float4 xb = x4[(r + 7) * 64 + l], yb = y4[(r + 7) * 64 + l];  // new, slide1
        float4 xc, yc, xd, yd;
        if (!lastit) {
            xc = x4[(r + 1) * 64 + l]; yc = y4[(r + 1) * 64 + l];     // old, slide2
            xd = x4[(r + 8) * 64 + l]; yd = y4[(r + 8) * 64 + l];     // new, slide2
        }

        // row r taps + SSIM
        float4 h0x  = taps7_shfl(sx);
        float4 h0y  = taps7_shfl(sy);
        float4 h0xx = taps7_shfl(sxx);
        float4 h0yy = taps7_shfl(syy);
        float4 h0xy = taps7_shfl(sxy);

        // slide to row r+1 window (overlaps ssim(h0) VALU with taps(r+1) DS)
        slide5(sx, sy, sxx, syy, sxy, xa, ya, xb, yb);

        float4 h1x  = taps7_shfl(sx);
        float4 h1y  = taps7_shfl(sy);
        float4 h1xx = taps7_shfl(sxx);
        float4 h1yy = taps7_shfl(syy);
        float4 h1xy = taps7_shfl(sxy);

        // lanes 0..61: all 4 valid; lane 62 (c0=248): 2 valid; lane 63: none
        if (c0 + 0 < OUTW) acc += ssim_px(h0x.x, h0y.x, h0xx.x, h0yy.x, h0xy.x, c1, c2)
                                + ssim_px(h1x.x, h1y.x, h1xx.x, h1yy.x, h1xy.x, c1, c2);
        if (c0 + 1 < OUTW) acc += ssim_px(h0x.y, h0y.y, h0xx.y, h0yy.y, h0xy.y, c1, c2)
                                + ssim_px(h1x.y, h1y.y, h1xx.y, h1yy.y, h1xy.y, c1, c2);
        if (c0 + 2 < OUTW) acc += ssim_px(h0x.z, h0y.z, h0xx.z, h0yy.z, h0xy.z, c1, c2)
                                + ssim_px(h1x.z, h1y.z, h1xx.z, h1yy.z, h1xy.z, c1, c2);
        if (c0 + 3 < OUTW) acc += ssim_px(h0x.w, h0y.w, h0xx.w, h0yy.w, h0xy.w, c1, c2)
                                + ssim_px(h1x.w, h1y.w, h1xx.w, h1yy.w, h1xy.w, c1, c2);

        if (!lastit)  // slide to row r+2 window for next iteration
            slide5(sx, sy, sxx, syy, sxy, xc, yc, xd, yd);
    }

    acc = wave_sum(acc);
    if (l == 0) partials[wid] = acc;
}

// ---------------- Pass 3: final reduce ----------------
__global__ __launch_bounds__(256) void final_kernel(const float* __restrict__ partials,
                                                    float* __restrict__ out) {
    float s = 0.f;
    for (int i = threadIdx.x; i < NWAVES; i += 256) s += partials[i];
    s = wave_sum(s);
    __shared__ float ssum[4];
    int lane = threadIdx.x & 63, w = threadIdx.x >> 6;
    if (lane == 0) ssum[w] = s;
    __syncthreads();
    if (threadIdx.x == 0) {
        float total = ssum[0] + ssum[1] + ssum[2] + ssum[3];
        const double denom = (double)NFRAMES * OUTW * OUTW;
        out[0] = (float)(1.0 - (double)total / denom);
    }
}

extern "C" void kernel_launch(void* const* d_in, const int* in_sizes, int n_in,
                              void* d_out, int out_size, void* d_ws, size_t ws_size,
                              hipStream_t stream) {
    const float* X = (const float*)d_in[0];
    const float* Y = (const float*)d_in[1];

    float* ws = (float*)d_ws;
    float* dr_part  = ws;                // [0 .. 1280)
    float* partials = ws + 2048;         // [2048 .. 2048+8000)

    dim3 g1(NT, NB * 4);
    hipLaunchKernelGGL(dr_max_kernel, g1, dim3(256), 0, stream, Y, dr_part);
    hipLaunchKernelGGL(ssim_kernel, dim3(NBLK2), dim3(256), 0, stream,
                       X, Y, (const float*)dr_part, partials);
    hipLaunchKernelGGL(final_kernel, dim3(1), dim3(256), 0, stream,
                       partials, (float*)d_out);
}

// Round 4
// 210.502 us; speedup vs baseline: 1.0870x; 1.0870x over previous
//
#include <hip/hip_runtime.h>

// SSIM loss: Xt, Yt are [B=16, C=1, T=20, H=256, W=256] fp32.
// Frame f = b*20 + t contiguous 65536 floats. dr[t] = max over Yt[:,:,t].
// S per 7x7 valid window (250x250/frame); out = 1 - mean(S).

#define HH 256
#define WW 256
#define OUTW 250
#define NT 20
#define NB 16
#define NFRAMES (NT * NB)        // 320
#define STRIPS 50
#define RPS 5                    // output rows per strip (50*5 = 250)
#define NWAVES (NFRAMES * STRIPS) // 16000
#define WPB 4                    // waves per block
#define NBLK2 (NWAVES / WPB)     // 4000
#define NXCD 8

__device__ __forceinline__ float wave_sum(float v) {
#pragma unroll
    for (int off = 32; off > 0; off >>= 1) v += __shfl_down(v, off, 64);
    return v;
}

// ---------------- Pass 1: per-t max over Yt (quarter-frame blocks) ----------
// Each block writes its max to a distinct slot dr_part[t*64 + bq]; ssim waves
// reduce the 64 slots (1 load + 6 shfl_xor). No atomics, no memset node.
__global__ __launch_bounds__(256) void dr_max_kernel(const float* __restrict__ Y,
                                                     float* __restrict__ dr_part) {
    int t = blockIdx.x;          // 0..19
    int bq = blockIdx.y;         // 0..63 : b = bq>>2, quarter = bq&3
    const float4* p = (const float4*)(Y + (size_t)((bq >> 2) * NT + t) * (HH * WW))
                      + (bq & 3) * 4096;
    float m = 0.f;               // inputs uniform [0,1) => non-negative
#pragma unroll 4
    for (int k = 0; k < 16; ++k) {
        float4 v = p[k * 256 + threadIdx.x];
        m = fmaxf(m, fmaxf(fmaxf(v.x, v.y), fmaxf(v.z, v.w)));
    }
#pragma unroll
    for (int off = 32; off > 0; off >>= 1) m = fmaxf(m, __shfl_down(m, off, 64));
    __shared__ float smax[4];
    int lane = threadIdx.x & 63, w = threadIdx.x >> 6;
    if (lane == 0) smax[w] = m;
    __syncthreads();
    if (threadIdx.x == 0)
        dr_part[t * 64 + bq] = fmaxf(fmaxf(smax[0], smax[1]), fmaxf(smax[2], smax[3]));
}

// ---------------- Pass 2: SSIM, 4 independent waves/block ------------------
// Each wave owns one (frame, strip); 64 lanes x 4 cols = 256 cols.
// Vertical 7-row running sums in registers; horizontal 7-tap via shuffles
// (zero LDS allocation). Inner loop is R8's exact no-spill 1-row/iter body
// (R9 proved staging 8 float4 across the row body spills: 24 MB scratch).
// R10: RPS 10->5 (16000 waves / 4000 blocks). R8's grid (2000 blocks) equaled
// residency capacity (VGPR44 -> 8 blk/CU x 256 CU = 2048): zero spare blocks,
// occupancy 41% << theoretical. 2x oversubscription keeps CUs full through
// ramp/tail. Plus bijective XCD swizzle: adjacent strips of a frame share
// 7/12 of their input rows; put them on the same XCD's L2.

// S scaled by 49^2 top & bottom (cancels): c1=2401*C1, c2=2401*C2.
__device__ __forceinline__ float ssim_px(float hx, float hy, float hxx, float hyy,
                                         float hxy, float c1, float c2) {
    const float cov = 49.0f / 48.0f;
    float hx2 = hx * hx, hy2 = hy * hy, hxy1 = hx * hy;
    float A1 = __builtin_fmaf(2.f, hxy1, c1);
    float B1 = hx2 + hy2 + c1;
    float t1 = __builtin_fmaf(49.f, hxx, -hx2);
    float t2 = __builtin_fmaf(49.f, hyy, -hy2);
    float t3 = __builtin_fmaf(49.f, hxy, -hxy1);
    float A2 = __builtin_fmaf(2.f * cov, t3, c2);
    float B2 = __builtin_fmaf(cov, t1 + t2, c2);
    return (A1 * A2) * __builtin_amdgcn_rcpf(B1 * B2);
}

// 7-tap horizontal sums for 4 consecutive output cols via cross-lane shuffles:
//   P = s.x+s.y+s.z+s.w;  P1 = P(lane+1), w1 = s.w(lane+1),
//   x2 = s.x(lane+2), y2 = s.y(lane+2)
//   o0 = P + P1 - w1; o1 = P + P1 - s.x; o2 = s.z+s.w+P1+x2; o3 = s.w+P1+x2+y2
// Lane 62: o0,o1 use lane-63 values (valid), o2,o3 masked. Lane 63: all masked.
__device__ __forceinline__ float4 taps7_shfl(float4 s) {
    float P  = (s.x + s.y) + (s.z + s.w);
    float P1 = __shfl_down(P,   1, 64);
    float w1 = __shfl_down(s.w, 1, 64);
    float x2 = __shfl_down(s.x, 2, 64);
    float y2 = __shfl_down(s.y, 2, 64);
    float base = P + P1;
    float o0 = base - w1;
    float o1 = base - s.x;
    float o2 = s.z + s.w + P1 + x2;
    float o3 = o2 - s.z + y2;          // s.w + P1 + x2 + y2
    return make_float4(o0, o1, o2, o3);
}

__device__ __forceinline__ void slide5(float4& sx, float4& sy, float4& sxx,
                                       float4& syy, float4& sxy,
                                       float4 xo, float4 yo, float4 xn, float4 yn) {
    sx.x += xn.x - xo.x; sx.y += xn.y - xo.y; sx.z += xn.z - xo.z; sx.w += xn.w - xo.w;
    sy.x += yn.x - yo.x; sy.y += yn.y - yo.y; sy.z += yn.z - yo.z; sy.w += yn.w - yo.w;
    sxx.x += xn.x * xn.x - xo.x * xo.x; sxx.y += xn.y * xn.y - xo.y * xo.y;
    sxx.z += xn.z * xn.z - xo.z * xo.z; sxx.w += xn.w * xn.w - xo.w * xo.w;
    syy.x += yn.x * yn.x - yo.x * yo.x; syy.y += yn.y * yn.y - yo.y * yo.y;
    syy.z += yn.z * yn.z - yo.z * yo.z; syy.w += yn.w * yn.w - yo.w * yo.w;
    sxy.x += xn.x * yn.x - xo.x * yo.x; sxy.y += xn.y * yn.y - xo.y * yo.y;
    sxy.z += xn.z * yn.z - xo.z * yo.z; sxy.w += xn.w * yn.w - xo.w * yo.w;
}

__global__ __launch_bounds__(256, 4) void ssim_kernel(const float* __restrict__ X,
                                                      const float* __restrict__ Y,
                                                      const float* __restrict__ dr_part,
                                                      float* __restrict__ partials) {
    int w = threadIdx.x >> 6;
    int l = threadIdx.x & 63;
    // Bijective XCD swizzle (NBLK2 % 8 == 0): blocks 0..499 -> XCD0, etc.
    // Consecutive swizzled blocks (same XCD) cover consecutive strips/frames.
    int bid = blockIdx.x;
    int swz = (bid % NXCD) * (NBLK2 / NXCD) + bid / NXCD;
    int wid = swz * WPB + w;
    int frame = wid / STRIPS;   // 0..319
    int strip = wid % STRIPS;   // 0..49
    int t = frame % NT;
    const float4* x4 = (const float4*)(X + (size_t)frame * (HH * WW));
    const float4* y4 = (const float4*)(Y + (size_t)frame * (HH * WW));
    int c0 = 4 * l;

    // dr[t] = max of the 64 per-block partial maxes (one per lane, butterfly)
    float dr = dr_part[t * 64 + l];
#pragma unroll
    for (int off = 32; off > 0; off >>= 1) dr = fmaxf(dr, __shfl_xor(dr, off, 64));
    float c1 = 2401.f * (0.01f * dr) * (0.01f * dr);
    float c2 = 2401.f * (0.03f * dr) * (0.03f * dr);

    int r0 = strip * RPS;

    // vertical running column-sums (4 cols/lane) over rows r0..r0+6
    float4 sx = make_float4(0, 0, 0, 0), sy = sx, sxx = sx, syy = sx, sxy = sx;
#pragma unroll
    for (int dy = 0; dy < 7; ++dy) {
        float4 xv = x4[(r0 + dy) * 64 + l];
        float4 yv = y4[(r0 + dy) * 64 + l];
        sx.x += xv.x; sx.y += xv.y; sx.z += xv.z; sx.w += xv.w;
        sy.x += yv.x; sy.y += yv.y; sy.z += yv.z; sy.w += yv.w;
        sxx.x += xv.x * xv.x; sxx.y += xv.y * xv.y; sxx.z += xv.z * xv.z; sxx.w += xv.w * xv.w;
        syy.x += yv.x * yv.x; syy.y += yv.y * yv.y; syy.z += yv.z * yv.z; syy.w += yv.w * yv.w;
        sxy.x += xv.x * yv.x; sxy.y += xv.y * yv.y; sxy.z += xv.z * yv.z; sxy.w += xv.w * yv.w;
    }

    float acc = 0.f;
    for (int it = 0; it < RPS; ++it) {
        int r = r0 + it;
        bool last = (it == RPS - 1);

        // issue next-row slide loads up front (latency hidden under shfl + math)
        float4 xo, yo, xn, yn;
        if (!last) {
            xo = x4[r * 64 + l];       yo = y4[r * 64 + l];
            xn = x4[(r + 7) * 64 + l]; yn = y4[(r + 7) * 64 + l];
        }

        float4 hx  = taps7_shfl(sx);
        float4 hy  = taps7_shfl(sy);
        float4 hxx = taps7_shfl(sxx);
        float4 hyy = taps7_shfl(syy);
        float4 hxy = taps7_shfl(sxy);

        // lanes 0..61: all 4 valid; lane 62 (c0=248): 2 valid; lane 63: none
        if (c0 + 0 < OUTW) acc += ssim_px(hx.x, hy.x, hxx.x, hyy.x, hxy.x, c1, c2);
        if (c0 + 1 < OUTW) acc += ssim_px(hx.y, hy.y, hxx.y, hyy.y, hxy.y, c1, c2);
        if (c0 + 2 < OUTW) acc += ssim_px(hx.z, hy.z, hxx.z, hyy.z, hxy.z, c1, c2);
        if (c0 + 3 < OUTW) acc += ssim_px(hx.w, hy.w, hxx.w, hyy.w, hxy.w, c1, c2);

        if (!last)
            slide5(sx, sy, sxx, syy, sxy, xo, yo, xn, yn);
    }

    acc = wave_sum(acc);
    if (l == 0) partials[wid] = acc;
}

// ---------------- Pass 3: final reduce ----------------
__global__ __launch_bounds__(256) void final_kernel(const float* __restrict__ partials,
                                                    float* __restrict__ out) {
    float s = 0.f;
    for (int i = threadIdx.x; i < NWAVES; i += 256) s += partials[i];
    s = wave_sum(s);
    __shared__ float ssum[4];
    int lane = threadIdx.x & 63, w = threadIdx.x >> 6;
    if (lane == 0) ssum[w] = s;
    __syncthreads();
    if (threadIdx.x == 0) {
        float total = ssum[0] + ssum[1] + ssum[2] + ssum[3];
        const double denom = (double)NFRAMES * OUTW * OUTW;
        out[0] = (float)(1.0 - (double)total / denom);
    }
}

extern "C" void kernel_launch(void* const* d_in, const int* in_sizes, int n_in,
                              void* d_out, int out_size, void* d_ws, size_t ws_size,
                              hipStream_t stream) {
    const float* X = (const float*)d_in[0];
    const float* Y = (const float*)d_in[1];

    float* ws = (float*)d_ws;
    float* dr_part  = ws;                // [0 .. 1280)
    float* partials = ws + 2048;         // [2048 .. 2048+16000)

    dim3 g1(NT, NB * 4);
    hipLaunchKernelGGL(dr_max_kernel, g1, dim3(256), 0, stream, Y, dr_part);
    hipLaunchKernelGGL(ssim_kernel, dim3(NBLK2), dim3(256), 0, stream,
                       X, Y, (const float*)dr_part, partials);
    hipLaunchKernelGGL(final_kernel, dim3(1), dim3(256), 0, stream,
                       partials, (float*)d_out);
}